// Round 2
// baseline (449.479 us; speedup 1.0000x reference)
//
#include <hip/hip_runtime.h>

#define NN 4096
#define EE 65536
#define HC 256   // hidden channels

typedef unsigned short ushort_t;
typedef __attribute__((ext_vector_type(8))) short bf16x8;
typedef __attribute__((ext_vector_type(4))) float f32x4;

__device__ __forceinline__ ushort_t f2bf(float f) {
    unsigned int u = __float_as_uint(f);
    unsigned int r = (u + 0x7fffu + ((u >> 16) & 1u)) >> 16;
    return (ushort_t)r;
}
__device__ __forceinline__ float bf2f(ushort_t u) {
    return __uint_as_float(((unsigned int)u) << 16);
}
// pack two floats to bf16 pair (round-half-up), a in low 16 (lower address)
__device__ __forceinline__ unsigned int pack2bf(float a, float b) {
    unsigned int ua = __float_as_uint(a) + 0x8000u;
    unsigned int ub = __float_as_uint(b) + 0x8000u;
    return __builtin_amdgcn_perm(ub, ua, 0x07060302u);
}

// ---------------- degree / CSR build ----------------
__global__ void deg_init_k(float* __restrict__ deg) {
    int i = blockIdx.x * 256 + threadIdx.x;
    deg[i] = 1.0f;  // self loop
}
__global__ void deg_scatter_k(const int* __restrict__ dst, float* __restrict__ deg) {
    int e = blockIdx.x * 256 + threadIdx.x;
    atomicAdd(&deg[dst[e]], 1.0f);
}
__global__ void dinv_k(const float* __restrict__ deg, float* __restrict__ dinv) {
    int i = blockIdx.x * 256 + threadIdx.x;
    dinv[i] = rsqrtf(deg[i]);
}
__global__ __launch_bounds__(1024)
void scan_offsets_k(const float* __restrict__ deg, int* __restrict__ offs,
                    int* __restrict__ cursor) {
    __shared__ int part[1024];
    const int t = threadIdx.x;
    int c0 = (int)deg[t * 4 + 0] - 1;
    int c1 = (int)deg[t * 4 + 1] - 1;
    int c2 = (int)deg[t * 4 + 2] - 1;
    int c3 = (int)deg[t * 4 + 3] - 1;
    part[t] = c0 + c1 + c2 + c3;
    __syncthreads();
    for (int off = 1; off < 1024; off <<= 1) {
        int v = (t >= off) ? part[t - off] : 0;
        __syncthreads();
        part[t] += v;
        __syncthreads();
    }
    int base = (t == 0) ? 0 : part[t - 1];
    offs[t * 4 + 0] = base;
    offs[t * 4 + 1] = base + c0;
    offs[t * 4 + 2] = base + c0 + c1;
    offs[t * 4 + 3] = base + c0 + c1 + c2;
    cursor[t * 4 + 0] = base;
    cursor[t * 4 + 1] = base + c0;
    cursor[t * 4 + 2] = base + c0 + c1;
    cursor[t * 4 + 3] = base + c0 + c1 + c2;
    if (t == 1023) offs[4096] = part[1023];
}
__global__ void csr_fill_k(const int* __restrict__ src, const int* __restrict__ dst,
                           int* __restrict__ cursor, int* __restrict__ csr_src) {
    int e = blockIdx.x * 256 + threadIdx.x;
    int pos = atomicAdd(&cursor[dst[e]], 1);
    csr_src[pos] = src[e];
}

// ---------------- GCN gather ----------------
__global__ __launch_bounds__(256)
void gcn_gather_k(const float* __restrict__ xw, const float* __restrict__ dinv,
                  const int* __restrict__ offs, const int* __restrict__ csr_src,
                  float* __restrict__ agg) {
    const int node = blockIdx.x * 4 + (threadIdx.x >> 6);
    const int c = (threadIdx.x & 63) * 4;
    const float dd = dinv[node];
    float4 a = *(const float4*)&xw[(size_t)node * HC + c];
    const float self = dd * dd;
    float4 acc = make_float4(a.x * self, a.y * self, a.z * self, a.w * self);
    const int beg = offs[node], end = offs[node + 1];
    for (int e = beg; e < end; e++) {
        int s = csr_src[e];
        float coef = dinv[s] * dd;
        const float4 v = *(const float4*)&xw[(size_t)s * HC + c];
        acc.x += v.x * coef;
        acc.y += v.y * coef;
        acc.z += v.z * coef;
        acc.w += v.w * coef;
    }
    *(float4*)&agg[(size_t)node * HC + c] = acc;
}

// ---------------- fp32 -> bf16 convert ----------------
__global__ void cvt_bf16_k(const float* __restrict__ in, ushort_t* __restrict__ out) {
    int i = (blockIdx.x * 256 + threadIdx.x) * 4;
    float4 v = *(const float4*)&in[i];
    unsigned int d0 = pack2bf(v.x, v.y), d1 = pack2bf(v.z, v.w);
    *(uint2*)&out[i] = make_uint2(d0, d1);
}

// ---------------- bf16-MFMA GEMM, 64row x 32col tile (2 blocks/CU+), dual region ----
__global__ __launch_bounds__(256)
void gemm_bf_k(const float* __restrict__ X, const float* __restrict__ W,
               const float* __restrict__ bias1, const float* __restrict__ bias2,
               const float* __restrict__ res1, const float* __restrict__ res2, float res2scale,
               float* __restrict__ out, int K, int M, int dorelu, int obf,
               int colsplit, const float* __restrict__ W2,
               const float* __restrict__ bias_r2, float* __restrict__ out2, int M2)
{
    __shared__ ushort_t As[64][72];
    __shared__ ushort_t Bs[32][72];
    const int t = threadIdx.x;
    const int w = t >> 6, lane = t & 63;
    const int m = lane & 15, quad = lane >> 4;
    const int row0 = blockIdx.y << 6, col0 = blockIdx.x << 5;   // 32-col tiles
    const int sr = t >> 2;
    const int sc = (t & 3) << 4;
    const int wr2 = t >> 3;           // W staging row 0..31
    const int wc2 = (t & 7) << 3;     // W staging k-chunk 0,8,...,56

    const float* Wu = W;
    const float* b1u = bias1;
    const float* b2u = bias2;
    float* outu = out;
    int Mu = M, colu = col0;
    if (colsplit > 0 && col0 >= colsplit) {
        Wu = W2; b1u = bias_r2; b2u = nullptr;
        outu = out2; Mu = M2; colu = col0 - colsplit;
    }

    f32x4 acc[2] = {};
    for (int k0 = 0; k0 < K; k0 += 64) {
        const float* xp = &X[(size_t)(row0 + sr) * K + k0 + sc];
        const float* wp = &Wu[(size_t)(colu + wr2) * K + k0 + wc2];
        float4 xa = *(const float4*)xp,       xb = *(const float4*)(xp + 4);
        float4 xc = *(const float4*)(xp + 8), xd = *(const float4*)(xp + 12);
        float4 wa = *(const float4*)wp,       wb = *(const float4*)(wp + 4);
        __syncthreads();
        {
            unsigned int tx[8];
            tx[0] = pack2bf(xa.x, xa.y); tx[1] = pack2bf(xa.z, xa.w);
            tx[2] = pack2bf(xb.x, xb.y); tx[3] = pack2bf(xb.z, xb.w);
            tx[4] = pack2bf(xc.x, xc.y); tx[5] = pack2bf(xc.z, xc.w);
            tx[6] = pack2bf(xd.x, xd.y); tx[7] = pack2bf(xd.z, xd.w);
            *(uint4*)&As[sr][sc]     = *(const uint4*)&tx[0];
            *(uint4*)&As[sr][sc + 8] = *(const uint4*)&tx[4];
            unsigned int tw[4];
            tw[0] = pack2bf(wa.x, wa.y); tw[1] = pack2bf(wa.z, wa.w);
            tw[2] = pack2bf(wb.x, wb.y); tw[3] = pack2bf(wb.z, wb.w);
            *(uint4*)&Bs[wr2][wc2] = *(const uint4*)&tw[0];
        }
        __syncthreads();
        #pragma unroll
        for (int kc = 0; kc < 2; kc++) {
            bf16x8 af = *(const bf16x8*)&As[(w << 4) + m][kc * 32 + quad * 8];
            #pragma unroll
            for (int cb = 0; cb < 2; cb++) {
                bf16x8 bf = *(const bf16x8*)&Bs[cb * 16 + m][kc * 32 + quad * 8];
                acc[cb] = __builtin_amdgcn_mfma_f32_16x16x32_bf16(af, bf, acc[cb], 0, 0, 0);
            }
        }
    }
    #pragma unroll
    for (int cb = 0; cb < 2; cb++) {
        #pragma unroll
        for (int r = 0; r < 4; r++) {
            const int row = row0 + (w << 4) + quad * 4 + r;
            const int col = colu + cb * 16 + m;
            float v = acc[cb][r];
            if (b1u) v += b1u[col];
            if (b2u) v += b2u[col];
            if (res1) v += res1[(size_t)row * Mu + col];
            if (res2) v += res2scale * res2[(size_t)row * Mu + col];
            if (dorelu) v = fmaxf(v, 0.f);
            if (obf) ((ushort_t*)outu)[(size_t)row * Mu + col] = f2bf(v);
            else outu[(size_t)row * Mu + col] = v;
        }
    }
}

// ---------------- K/V bf16 prep: Kb[h][n][d], Vtb[h][d][n] ----------------
__global__ __launch_bounds__(256)
void kv_prep_k(const float* __restrict__ qkv, ushort_t* __restrict__ Kb,
               ushort_t* __restrict__ Vtb)
{
    __shared__ ushort_t Vs[64][72];
    const int h = blockIdx.y;
    const int n0 = blockIdx.x << 6;
    const int t = threadIdx.x;
    for (int u = t; u < 1024; u += 256) {
        int r = u >> 4, c = u & 15;
        const float* kp = &qkv[(size_t)(n0 + r) * 768 + 256 + h * 64 + c * 4];
        float4 kv = *(const float4*)kp;
        float4 vv = *(const float4*)(kp + 256);
        *(uint2*)&Kb[((size_t)(h * 4096 + n0 + r)) * 64 + c * 4] =
            make_uint2(pack2bf(kv.x, kv.y), pack2bf(kv.z, kv.w));
        *(uint2*)&Vs[r][c * 4] =
            make_uint2(pack2bf(vv.x, vv.y), pack2bf(vv.z, vv.w));
    }
    __syncthreads();
    int d = t >> 2, kc = t & 3;
    __attribute__((aligned(16))) ushort_t vals[16];
    #pragma unroll
    for (int k = 0; k < 16; k++) vals[k] = Vs[kc * 16 + k][d];
    ushort_t* op = &Vtb[((size_t)(h * 64 + d)) * 4096 + n0 + kc * 16];
    *(uint4*)op = *(const uint4*)&vals[0];
    *(uint4*)(op + 8) = *(const uint4*)&vals[8];
}

// ---------------- split-K MFMA flash attention partials (exp2 domain) ----------------
// v3: raw s_barrier + lgkmcnt(0) (no vmcnt drain in main loop), K double-buffered
//     in LDS, V single-buffered; global loads stay in flight a full iteration.
//     Keeps T13 defer-max and T5 setprio from v2.
__global__ __launch_bounds__(256)
void attn_part_k(const float* qkv, const ushort_t* __restrict__ Kb,
                 const ushort_t* __restrict__ Vtb, ushort_t* opart,
                 float* __restrict__ m_part, float* __restrict__ l_part)
{
    __shared__ ushort_t Kt[2][64][72];
    __shared__ ushort_t Vt[64][72];
    __shared__ ushort_t Plb[4][16][72];
    const int h = blockIdx.y & 3;
    const int split = blockIdx.y >> 2;
    const int q0 = blockIdx.x << 6;
    const int t = threadIdx.x;
    const int w = t >> 6, lane = t & 63;
    const int m = lane & 15, quad = lane >> 4;

    // ---- staging geometry: thread covers rows r0 and r0+32, 16B col chunk
    const int r0 = t >> 3, c8 = (t & 7) << 3;
    const int r1 = r0 + 32;
    const int pr0 = ((r0 & 15) << 2) | (r0 >> 4);   // permuted key row for Kt
    const int pr1 = ((r1 & 15) << 2) | (r1 >> 4);
    const ushort_t* kb_p0 = &Kb[((size_t)(h * 4096 + split * 1024 + pr0)) * 64 + c8];
    const ushort_t* kb_p1 = &Kb[((size_t)(h * 4096 + split * 1024 + pr1)) * 64 + c8];
    const ushort_t* vt_p0 = &Vtb[((size_t)(h * 64 + r0)) * 4096 + split * 1024 + c8];
    const ushort_t* vt_p1 = &Vtb[((size_t)(h * 64 + r1)) * 4096 + split * 1024 + c8];

    // Q prescaled by 0.125*log2(e): scores land in log2 domain
    const float qs = 0.125f * 1.44269504f;
    bf16x8 qf[2];
    #pragma unroll
    for (int kc = 0; kc < 2; kc++) {
        const float* qp = &qkv[(size_t)(q0 + w * 16 + m) * 768 + h * 64 + kc * 32 + quad * 8];
        float4 a = *(const float4*)qp;
        float4 b = *(const float4*)(qp + 4);
        qf[kc][0] = (short)f2bf(a.x * qs);
        qf[kc][1] = (short)f2bf(a.y * qs);
        qf[kc][2] = (short)f2bf(a.z * qs);
        qf[kc][3] = (short)f2bf(a.w * qs);
        qf[kc][4] = (short)f2bf(b.x * qs);
        qf[kc][5] = (short)f2bf(b.y * qs);
        qf[kc][6] = (short)f2bf(b.z * qs);
        qf[kc][7] = (short)f2bf(b.w * qs);
    }
    bf16x8 onesf;
    #pragma unroll
    for (int j = 0; j < 8; j++) onesf[j] = (short)0x3F80;

    f32x4 o[4], ol;
    float mrow[4];
    #pragma unroll
    for (int i = 0; i < 4; i++) {
        o[i] = (f32x4){0.f, 0.f, 0.f, 0.f};
        mrow[i] = -1e30f;
    }
    ol = (f32x4){0.f, 0.f, 0.f, 0.f};

    // ---- prologue: K(tile0) -> Kt[0]; V(tile0) and K(tile1) in registers
    uint4 ka = *(const uint4*)kb_p0;
    uint4 kb4 = *(const uint4*)kb_p1;
    uint4 va = *(const uint4*)vt_p0;
    uint4 vb = *(const uint4*)vt_p1;
    *(uint4*)&Kt[0][r0][c8] = ka;
    *(uint4*)&Kt[0][r1][c8] = kb4;
    kb_p0 += 4096; kb_p1 += 4096;
    ka = *(const uint4*)kb_p0;      // K(tile1), in flight
    kb4 = *(const uint4*)kb_p1;

    for (int it = 0; it < 16; it++) {
        // ---- barrier A: prev iteration's LDS reads done; NO vmcnt drain
        asm volatile("s_waitcnt lgkmcnt(0)" ::: "memory");
        __builtin_amdgcn_s_barrier();
        asm volatile("" ::: "memory");
        // write V(tile it); write K(tile it+1) into the other buffer
        *(uint4*)&Vt[r0][c8] = va;
        *(uint4*)&Vt[r1][c8] = vb;
        if (it < 15) {
            ushort_t (*KtW)[72] = Kt[(it + 1) & 1];
            *(uint4*)&KtW[r0][c8] = ka;
            *(uint4*)&KtW[r1][c8] = kb4;
            // issue V(tile it+1): rides under QK+softmax+PV
            vt_p0 += 64; vt_p1 += 64;
            va = *(const uint4*)vt_p0;
            vb = *(const uint4*)vt_p1;
        }
        if (it < 14) {
            // issue K(tile it+2): rides a full iteration
            kb_p0 += 4096; kb_p1 += 4096;
            ka = *(const uint4*)kb_p0;
            kb4 = *(const uint4*)kb_p1;
        }

        // ---- QK^T from Kt[it&1] (written a full iteration ago)
        const ushort_t (*KtR)[72] = Kt[it & 1];
        f32x4 s[4];
        #pragma unroll
        for (int b = 0; b < 4; b++) s[b] = (f32x4){0.f, 0.f, 0.f, 0.f};
        __builtin_amdgcn_s_setprio(1);
        #pragma unroll
        for (int b = 0; b < 4; b++)
            #pragma unroll
            for (int kc = 0; kc < 2; kc++) {
                bf16x8 kf = *(const bf16x8*)&KtR[b * 16 + m][kc * 32 + quad * 8];
                s[b] = __builtin_amdgcn_mfma_f32_16x16x32_bf16(qf[kc], kf, s[b], 0, 0, 0);
            }
        __builtin_amdgcn_s_setprio(0);

        // row max (uniform across the 16 m-lanes after the butterfly)
        float mx[4];
        #pragma unroll
        for (int r = 0; r < 4; r++) {
            float v = fmaxf(fmaxf(s[0][r], s[1][r]), fmaxf(s[2][r], s[3][r]));
            #pragma unroll
            for (int off = 1; off < 16; off <<= 1)
                v = fmaxf(v, __shfl_xor(v, off));
            mx[r] = v;
        }
        // T13 defer-max: only rescale when some row's max grew by > 8 (log2)
        bool grow = (mx[0] > mrow[0] + 8.f) | (mx[1] > mrow[1] + 8.f) |
                    (mx[2] > mrow[2] + 8.f) | (mx[3] > mrow[3] + 8.f);
        if (__any(grow)) {
            #pragma unroll
            for (int r = 0; r < 4; r++) {
                float mn = fmaxf(mrow[r], mx[r]);
                float alpha = __builtin_amdgcn_exp2f(mrow[r] - mn);
                mrow[r] = mn;
                o[0][r] *= alpha; o[1][r] *= alpha;
                o[2][r] *= alpha; o[3][r] *= alpha;
                ol[r] *= alpha;
            }
        }
        #pragma unroll
        for (int r = 0; r < 4; r++) {
            unsigned int d0 = pack2bf(__builtin_amdgcn_exp2f(s[0][r] - mrow[r]),
                                      __builtin_amdgcn_exp2f(s[1][r] - mrow[r]));
            unsigned int d1 = pack2bf(__builtin_amdgcn_exp2f(s[2][r] - mrow[r]),
                                      __builtin_amdgcn_exp2f(s[3][r] - mrow[r]));
            *(uint2*)&Plb[w][quad * 4 + r][m * 4] = make_uint2(d0, d1);
        }

        // ---- barrier B: Vt writes visible; prefetch loads stay in flight
        asm volatile("s_waitcnt lgkmcnt(0)" ::: "memory");
        __builtin_amdgcn_s_barrier();
        asm volatile("" ::: "memory");

        __builtin_amdgcn_s_setprio(1);
        #pragma unroll
        for (int kc = 0; kc < 2; kc++) {
            bf16x8 pa = *(const bf16x8*)&Plb[w][m][kc * 32 + quad * 8];
            #pragma unroll
            for (int nb = 0; nb < 4; nb++) {
                bf16x8 vf = *(const bf16x8*)&Vt[nb * 16 + m][kc * 32 + quad * 8];
                o[nb] = __builtin_amdgcn_mfma_f32_16x16x32_bf16(pa, vf, o[nb], 0, 0, 0);
            }
            ol = __builtin_amdgcn_mfma_f32_16x16x32_bf16(pa, onesf, ol, 0, 0, 0);
        }
        __builtin_amdgcn_s_setprio(0);
    }

    #pragma unroll
    for (int nb = 0; nb < 4; nb++)
        #pragma unroll
        for (int r = 0; r < 4; r++) {
            int q = q0 + w * 16 + quad * 4 + r;
            opart[(size_t)q * 1536 + 512 + split * 256 + h * 64 + nb * 16 + m] = f2bf(o[nb][r]);
        }
    if (m == 0) {
        #pragma unroll
        for (int r = 0; r < 4; r++) {
            int q = q0 + w * 16 + quad * 4 + r;
            m_part[(split * 4 + h) * 4096 + q] = mrow[r];
            l_part[(split * 4 + h) * 4096 + q] = ol[r];
        }
    }
}

// merge 4 splits (m in log2 domain)
__global__ __launch_bounds__(256)
void attn_merge_k(const ushort_t* __restrict__ opart, const float* __restrict__ m_part,
                  const float* __restrict__ l_part, float* __restrict__ att)
{
    int idx = blockIdx.x * 256 + threadIdx.x;
    int q = idx >> 8, c = idx & 255;
    int h = c >> 6, d = c & 63;
    float ms[4];
    float mmax = -1e30f;
    #pragma unroll
    for (int s = 0; s < 4; s++) {
        ms[s] = m_part[(s * 4 + h) * 4096 + q];
        mmax = fmaxf(mmax, ms[s]);
    }
    float onum = 0.f, lden = 0.f;
    #pragma unroll
    for (int s = 0; s < 4; s++) {
        float wgt = __builtin_amdgcn_exp2f(ms[s] - mmax);
        float ov = bf2f(opart[(size_t)q * 1536 + 512 + s * 256 + h * 64 + d]);
        onum += wgt * ov;
        lden += wgt * l_part[(s * 4 + h) * 4096 + q];
    }
    att[(size_t)q * 256 + c] = onum / lden;
}

// ---------------- symmetrized final MLP, MFMA bf16 ----------------
__global__ __launch_bounds__(256)
void sym_mlp_mfma_k(const ushort_t* __restrict__ Tb, const ushort_t* __restrict__ Wb,
                    const float* __restrict__ b2, float* __restrict__ out)
{
    __shared__ ushort_t As[128][72];
    __shared__ ushort_t Bs[128][72];
    const int t = threadIdx.x;
    const int w = t >> 6, lane = t & 63;
    const int m = lane & 15, quad = lane >> 4;
    const int wr = (w >> 1) * 64, wc = (w & 1) * 64;
    const int ri = blockIdx.y * 128, rj = blockIdx.x * 128;

    f32x4 acc[4][4] = {};
    for (int kk = 0; kk < 8; kk++) {
        const int k0 = kk * 64;
        const ushort_t* Asrc = (k0 < 256) ? Tb : Wb;
        const ushort_t* Bsrc = (k0 < 256) ? Wb : Tb;
        const int kcol = k0 & 255;
        __syncthreads();
        #pragma unroll
        for (int i = 0; i < 4; i++) {
            int s = t + i * 256;
            int row = s >> 3, ch = (s & 7) * 8;
            *(uint4*)&As[row][ch] = *(const uint4*)&Asrc[(size_t)(ri + row) * 256 + kcol + ch];
            *(uint4*)&Bs[row][ch] = *(const uint4*)&Bsrc[(size_t)(rj + row) * 256 + kcol + ch];
        }
        __syncthreads();
        #pragma unroll
        for (int kc = 0; kc < 2; kc++) {
            bf16x8 af[4], bfr[4];
            #pragma unroll
            for (int rb = 0; rb < 4; rb++)
                af[rb] = *(const bf16x8*)&As[wr + rb * 16 + m][kc * 32 + quad * 8];
            #pragma unroll
            for (int cb = 0; cb < 4; cb++)
                bfr[cb] = *(const bf16x8*)&Bs[wc + cb * 16 + m][kc * 32 + quad * 8];
            #pragma unroll
            for (int rb = 0; rb < 4; rb++)
                #pragma unroll
                for (int cb = 0; cb < 4; cb++)
                    acc[rb][cb] = __builtin_amdgcn_mfma_f32_16x16x32_bf16(af[rb], bfr[cb], acc[rb][cb], 0, 0, 0);
        }
    }
    #pragma unroll
    for (int rb = 0; rb < 4; rb++) {
        #pragma unroll
        for (int r = 0; r < 4; r++) {
            const int gr = ri + wr + rb * 16 + quad * 4 + r;
            const float br = b2[gr];
            #pragma unroll
            for (int cb = 0; cb < 4; cb++) {
                const int gc = rj + wc + cb * 16 + m;
                out[(size_t)gr * NN + gc] = 0.5f * (acc[rb][cb][r] + br + b2[gc]);
            }
        }
    }
}

// ---------------- launch ----------------
extern "C" void kernel_launch(void* const* d_in, const int* in_sizes, int n_in,
                              void* d_out, int out_size, void* d_ws, size_t ws_size,
                              hipStream_t stream) {
    (void)in_sizes; (void)n_in; (void)out_size; (void)ws_size;
    const float* x = (const float*)d_in[0];
    const int* ei = (const int*)d_in[1];
    const int* src = ei;
    const int* dst = ei + EE;

    float* ws = (float*)d_ws;
    const int NH = NN * HC;          // 1,048,576 floats
    float* h0  = ws;
    float* hb  = ws + 1 * NH;
    float* hc  = ws + 2 * NH;
    float* att = ws + 3 * NH;
    float* qkv = ws + 4 * NH;
    float* ffh = ws + 4 * NH;        // reuses qkv region (dead by then)
    float* deg = ws + 7 * NH;
    float* dinv = deg + NN;
    int* offs    = (int*)(dinv + NN);
    int* cursor  = offs + 4100;
    int* csr_src = cursor + 4096;
    float* m_part = (float*)(csr_src + EE);
    float* l_part = m_part + 65536;
    ushort_t* Kb  = (ushort_t*)hc;
    ushort_t* Vtb = Kb + NH;
    ushort_t* Tb  = (ushort_t*)hb;
    ushort_t* W2b = Tb + NH;

    deg_init_k<<<NN / 256, 256, 0, stream>>>(deg);
    deg_scatter_k<<<EE / 256, 256, 0, stream>>>(dst, deg);
    dinv_k<<<NN / 256, 256, 0, stream>>>(deg, dinv);
    scan_offsets_k<<<1, 1024, 0, stream>>>(deg, offs, cursor);
    csr_fill_k<<<EE / 256, 256, 0, stream>>>(src, dst, cursor, csr_src);

    // pre: h0 = relu(x @ pre_w^T + pre_b)
    gemm_bf_k<<<dim3(8, 64), 256, 0, stream>>>(
        x, (const float*)d_in[2], (const float*)d_in[3], nullptr,
        nullptr, nullptr, 0.f, h0, 128, 256, 1, 0,
        0, nullptr, nullptr, nullptr, 0);

    for (int L = 0; L < 2; L++) {
        int B = 4 + L * 10;
        const float* gw = (const float*)d_in[B + 0];
        const float* gb = (const float*)d_in[B + 1];
        const float* iw = (const float*)d_in[B + 2];
        const float* ib = (const float*)d_in[B + 3];
        const float* ow = (const float*)d_in[B + 4];
        const float* ob = (const float*)d_in[B + 5];
        const float* w1 = (const float*)d_in[B + 6];
        const float* b1 = (const float*)d_in[B + 7];
        const float* w2 = (const float*)d_in[B + 8];
        const float* b2 = (const float*)d_in[B + 9];

        // fused: cols 0-255 = h0@gw^T -> att(xw); cols 256-1023 = h0@iw^T+ib -> qkv
        gemm_bf_k<<<dim3(32, 64), 256, 0, stream>>>(
            h0, gw, nullptr, nullptr, nullptr, nullptr, 0.f, att, 256, 256, 0, 0,
            256, iw, ib, qkv, 768);
        gcn_gather_k<<<NN / 4, 256, 0, stream>>>(att, dinv, offs, csr_src, hb);
        kv_prep_k<<<dim3(64, 4), 256, 0, stream>>>(qkv, Kb, Vtb);
        attn_part_k<<<dim3(64, 16), 256, 0, stream>>>(
            qkv, Kb, Vtb, (ushort_t*)qkv, m_part, l_part);
        attn_merge_k<<<NN, 256, 0, stream>>>(
            (const ushort_t*)qkv, m_part, l_part, att);
        gemm_bf_k<<<dim3(8, 64), 256, 0, stream>>>(
            att, ow, ob, gb, hb, h0, 2.0f, hc, 256, 256, 0, 0,
            0, nullptr, nullptr, nullptr, 0);
        gemm_bf_k<<<dim3(16, 64), 256, 0, stream>>>(
            hc, w1, b1, nullptr, nullptr, nullptr, 0.f, ffh, 256, 512, 1, 0,
            0, nullptr, nullptr, nullptr, 0);
        gemm_bf_k<<<dim3(8, 64), 256, 0, stream>>>(
            ffh, w2, b2, nullptr, hc, nullptr, 0.f, h0, 512, 256, 1, 0,
            0, nullptr, nullptr, nullptr, 0);
    }

    // Tb(bf16) = relu(h0 @ mlp_w1^T + mlp_b1)
    gemm_bf_k<<<dim3(8, 64), 256, 0, stream>>>(
        h0, (const float*)d_in[24], (const float*)d_in[25], nullptr,
        nullptr, nullptr, 0.f, (float*)Tb, 256, 256, 1, 1,
        0, nullptr, nullptr, nullptr, 0);
    // W2b = bf16(mlp_w2)
    cvt_bf16_k<<<NH / 1024, 256, 0, stream>>>((const float*)d_in[26], W2b);
    // out = 0.5*(delta + delta^T) via K=512 concat GEMM
    sym_mlp_mfma_k<<<dim3(32, 32), 256, 0, stream>>>(
        Tb, W2b, (const float*)d_in[27], (float*)d_out);
}

// Round 3
// 419.991 us; speedup vs baseline: 1.0702x; 1.0702x over previous
//
#include <hip/hip_runtime.h>

#define NN 4096
#define EE 65536
#define HC 256   // hidden channels

typedef unsigned short ushort_t;
typedef __attribute__((ext_vector_type(8))) short bf16x8;
typedef __attribute__((ext_vector_type(4))) float f32x4;
typedef __attribute__((ext_vector_type(16))) float f32x16;

__device__ __forceinline__ ushort_t f2bf(float f) {
    unsigned int u = __float_as_uint(f);
    unsigned int r = (u + 0x7fffu + ((u >> 16) & 1u)) >> 16;
    return (ushort_t)r;
}
__device__ __forceinline__ float bf2f(ushort_t u) {
    return __uint_as_float(((unsigned int)u) << 16);
}
// pack two floats to bf16 pair (round-half-up), a in low 16 (lower address)
__device__ __forceinline__ unsigned int pack2bf(float a, float b) {
    unsigned int ua = __float_as_uint(a) + 0x8000u;
    unsigned int ub = __float_as_uint(b) + 0x8000u;
    return __builtin_amdgcn_perm(ub, ua, 0x07060302u);
}

// ---------------- degree / CSR build ----------------
__global__ void deg_init_k(float* __restrict__ deg) {
    int i = blockIdx.x * 256 + threadIdx.x;
    deg[i] = 1.0f;  // self loop
}
__global__ void deg_scatter_k(const int* __restrict__ dst, float* __restrict__ deg) {
    int e = blockIdx.x * 256 + threadIdx.x;
    atomicAdd(&deg[dst[e]], 1.0f);
}
__global__ void dinv_k(const float* __restrict__ deg, float* __restrict__ dinv) {
    int i = blockIdx.x * 256 + threadIdx.x;
    dinv[i] = rsqrtf(deg[i]);
}
__global__ __launch_bounds__(1024)
void scan_offsets_k(const float* __restrict__ deg, int* __restrict__ offs,
                    int* __restrict__ cursor) {
    __shared__ int part[1024];
    const int t = threadIdx.x;
    int c0 = (int)deg[t * 4 + 0] - 1;
    int c1 = (int)deg[t * 4 + 1] - 1;
    int c2 = (int)deg[t * 4 + 2] - 1;
    int c3 = (int)deg[t * 4 + 3] - 1;
    part[t] = c0 + c1 + c2 + c3;
    __syncthreads();
    for (int off = 1; off < 1024; off <<= 1) {
        int v = (t >= off) ? part[t - off] : 0;
        __syncthreads();
        part[t] += v;
        __syncthreads();
    }
    int base = (t == 0) ? 0 : part[t - 1];
    offs[t * 4 + 0] = base;
    offs[t * 4 + 1] = base + c0;
    offs[t * 4 + 2] = base + c0 + c1;
    offs[t * 4 + 3] = base + c0 + c1 + c2;
    cursor[t * 4 + 0] = base;
    cursor[t * 4 + 1] = base + c0;
    cursor[t * 4 + 2] = base + c0 + c1;
    cursor[t * 4 + 3] = base + c0 + c1 + c2;
    if (t == 1023) offs[4096] = part[1023];
}
__global__ void csr_fill_k(const int* __restrict__ src, const int* __restrict__ dst,
                           int* __restrict__ cursor, int* __restrict__ csr_src) {
    int e = blockIdx.x * 256 + threadIdx.x;
    int pos = atomicAdd(&cursor[dst[e]], 1);
    csr_src[pos] = src[e];
}

// ---------------- GCN gather ----------------
__global__ __launch_bounds__(256)
void gcn_gather_k(const float* __restrict__ xw, const float* __restrict__ dinv,
                  const int* __restrict__ offs, const int* __restrict__ csr_src,
                  float* __restrict__ agg) {
    const int node = blockIdx.x * 4 + (threadIdx.x >> 6);
    const int c = (threadIdx.x & 63) * 4;
    const float dd = dinv[node];
    float4 a = *(const float4*)&xw[(size_t)node * HC + c];
    const float self = dd * dd;
    float4 acc = make_float4(a.x * self, a.y * self, a.z * self, a.w * self);
    const int beg = offs[node], end = offs[node + 1];
    for (int e = beg; e < end; e++) {
        int s = csr_src[e];
        float coef = dinv[s] * dd;
        const float4 v = *(const float4*)&xw[(size_t)s * HC + c];
        acc.x += v.x * coef;
        acc.y += v.y * coef;
        acc.z += v.z * coef;
        acc.w += v.w * coef;
    }
    *(float4*)&agg[(size_t)node * HC + c] = acc;
}

// ---------------- fp32 -> bf16 convert ----------------
__global__ void cvt_bf16_k(const float* __restrict__ in, ushort_t* __restrict__ out) {
    int i = (blockIdx.x * 256 + threadIdx.x) * 4;
    float4 v = *(const float4*)&in[i];
    unsigned int d0 = pack2bf(v.x, v.y), d1 = pack2bf(v.z, v.w);
    *(uint2*)&out[i] = make_uint2(d0, d1);
}

// ---------------- bf16-MFMA GEMM, 64row x 32col tile (2 blocks/CU+), dual region ----
__global__ __launch_bounds__(256)
void gemm_bf_k(const float* __restrict__ X, const float* __restrict__ W,
               const float* __restrict__ bias1, const float* __restrict__ bias2,
               const float* __restrict__ res1, const float* __restrict__ res2, float res2scale,
               float* __restrict__ out, int K, int M, int dorelu, int obf,
               int colsplit, const float* __restrict__ W2,
               const float* __restrict__ bias_r2, float* __restrict__ out2, int M2)
{
    __shared__ ushort_t As[64][72];
    __shared__ ushort_t Bs[32][72];
    const int t = threadIdx.x;
    const int w = t >> 6, lane = t & 63;
    const int m = lane & 15, quad = lane >> 4;
    const int row0 = blockIdx.y << 6, col0 = blockIdx.x << 5;   // 32-col tiles
    const int sr = t >> 2;
    const int sc = (t & 3) << 4;
    const int wr2 = t >> 3;           // W staging row 0..31
    const int wc2 = (t & 7) << 3;     // W staging k-chunk 0,8,...,56

    const float* Wu = W;
    const float* b1u = bias1;
    const float* b2u = bias2;
    float* outu = out;
    int Mu = M, colu = col0;
    if (colsplit > 0 && col0 >= colsplit) {
        Wu = W2; b1u = bias_r2; b2u = nullptr;
        outu = out2; Mu = M2; colu = col0 - colsplit;
    }

    f32x4 acc[2] = {};
    for (int k0 = 0; k0 < K; k0 += 64) {
        const float* xp = &X[(size_t)(row0 + sr) * K + k0 + sc];
        const float* wp = &Wu[(size_t)(colu + wr2) * K + k0 + wc2];
        float4 xa = *(const float4*)xp,       xb = *(const float4*)(xp + 4);
        float4 xc = *(const float4*)(xp + 8), xd = *(const float4*)(xp + 12);
        float4 wa = *(const float4*)wp,       wb = *(const float4*)(wp + 4);
        __syncthreads();
        {
            unsigned int tx[8];
            tx[0] = pack2bf(xa.x, xa.y); tx[1] = pack2bf(xa.z, xa.w);
            tx[2] = pack2bf(xb.x, xb.y); tx[3] = pack2bf(xb.z, xb.w);
            tx[4] = pack2bf(xc.x, xc.y); tx[5] = pack2bf(xc.z, xc.w);
            tx[6] = pack2bf(xd.x, xd.y); tx[7] = pack2bf(xd.z, xd.w);
            *(uint4*)&As[sr][sc]     = *(const uint4*)&tx[0];
            *(uint4*)&As[sr][sc + 8] = *(const uint4*)&tx[4];
            unsigned int tw[4];
            tw[0] = pack2bf(wa.x, wa.y); tw[1] = pack2bf(wa.z, wa.w);
            tw[2] = pack2bf(wb.x, wb.y); tw[3] = pack2bf(wb.z, wb.w);
            *(uint4*)&Bs[wr2][wc2] = *(const uint4*)&tw[0];
        }
        __syncthreads();
        #pragma unroll
        for (int kc = 0; kc < 2; kc++) {
            bf16x8 af = *(const bf16x8*)&As[(w << 4) + m][kc * 32 + quad * 8];
            #pragma unroll
            for (int cb = 0; cb < 2; cb++) {
                bf16x8 bf = *(const bf16x8*)&Bs[cb * 16 + m][kc * 32 + quad * 8];
                acc[cb] = __builtin_amdgcn_mfma_f32_16x16x32_bf16(af, bf, acc[cb], 0, 0, 0);
            }
        }
    }
    #pragma unroll
    for (int cb = 0; cb < 2; cb++) {
        #pragma unroll
        for (int r = 0; r < 4; r++) {
            const int row = row0 + (w << 4) + quad * 4 + r;
            const int col = colu + cb * 16 + m;
            float v = acc[cb][r];
            if (b1u) v += b1u[col];
            if (b2u) v += b2u[col];
            if (res1) v += res1[(size_t)row * Mu + col];
            if (res2) v += res2scale * res2[(size_t)row * Mu + col];
            if (dorelu) v = fmaxf(v, 0.f);
            if (obf) ((ushort_t*)outu)[(size_t)row * Mu + col] = f2bf(v);
            else outu[(size_t)row * Mu + col] = v;
        }
    }
}

// ---------------- K/V bf16 prep: Kb[h][n][d], Vtb[h][d][n] ----------------
__global__ __launch_bounds__(256)
void kv_prep_k(const float* __restrict__ qkv, ushort_t* __restrict__ Kb,
               ushort_t* __restrict__ Vtb)
{
    __shared__ ushort_t Vs[64][72];
    const int h = blockIdx.y;
    const int n0 = blockIdx.x << 6;
    const int t = threadIdx.x;
    for (int u = t; u < 1024; u += 256) {
        int r = u >> 4, c = u & 15;
        const float* kp = &qkv[(size_t)(n0 + r) * 768 + 256 + h * 64 + c * 4];
        float4 kv = *(const float4*)kp;
        float4 vv = *(const float4*)(kp + 256);
        *(uint2*)&Kb[((size_t)(h * 4096 + n0 + r)) * 64 + c * 4] =
            make_uint2(pack2bf(kv.x, kv.y), pack2bf(kv.z, kv.w));
        *(uint2*)&Vs[r][c * 4] =
            make_uint2(pack2bf(vv.x, vv.y), pack2bf(vv.z, vv.w));
    }
    __syncthreads();
    int d = t >> 2, kc = t & 3;
    __attribute__((aligned(16))) ushort_t vals[16];
    #pragma unroll
    for (int k = 0; k < 16; k++) vals[k] = Vs[kc * 16 + k][d];
    ushort_t* op = &Vtb[((size_t)(h * 64 + d)) * 4096 + n0 + kc * 16];
    *(uint4*)op = *(const uint4*)&vals[0];
    *(uint4*)(op + 8) = *(const uint4*)&vals[8];
}

// ---------------- split-K MFMA flash attention partials (exp2 domain) ----------------
// v4: swapped-QK^T 32x32x16 structure (T12): S = mfma(K, Q) so each lane owns the
//     P-row of its q = lane&31. Softmax fully lane-local (fmax tree + one xor-32
//     shuffle), P packed to bf16 in-register and fed to PV directly (no Plb LDS
//     round trip, no 4-deep shuffle butterflies). K/V tiles in XOR-swizzled
//     [64][64] LDS (byte ^= (row&7)<<4). 2 warps x 32 q per block, 1024 blocks.
__global__ __launch_bounds__(128)
void attn_part_k(const float* qkv, const ushort_t* __restrict__ Kb,
                 const ushort_t* __restrict__ Vtb, ushort_t* opart,
                 float* __restrict__ m_part, float* __restrict__ l_part)
{
    __shared__ ushort_t Kt[64][64];   // [k][d], row-major, col16 ^= (row&7)
    __shared__ ushort_t Vt[64][64];   // [d][k], row-major, col16 ^= (row&7)
    const int h = blockIdx.y & 3;
    const int split = blockIdx.y >> 2;
    const int q0 = blockIdx.x << 6;
    const int t = threadIdx.x;
    const int w = t >> 6;
    const int lane = t & 63;
    const int l31 = lane & 31;
    const int hi = lane >> 5;

    // staging geometry: thread covers rows sr, sr+16, sr+32, sr+48, 16B chunk sc
    const int sr = t >> 3;            // 0..15
    const int sc = t & 7;
    const int swz = ((sc ^ (sr & 7)) << 3);   // (sr+16k)&7 == sr&7
    const ushort_t* kp = &Kb[((size_t)(h * 4096 + split * 1024 + sr)) * 64 + sc * 8];
    const ushort_t* vp = &Vtb[((size_t)(h * 64 + sr)) * 4096 + split * 1024 + sc * 8];

    // Q fragments (B-operand): lane holds Q[d = s*16 + hi*8 + j][q = l31]
    const float qs = 0.125f * 1.44269504f;
    const int qrow = q0 + w * 32 + l31;
    bf16x8 qf[4];
    #pragma unroll
    for (int s = 0; s < 4; s++) {
        const float* qp = &qkv[(size_t)qrow * 768 + h * 64 + s * 16 + hi * 8];
        float4 a = *(const float4*)qp;
        float4 b = *(const float4*)(qp + 4);
        union { uint4 u; bf16x8 v; } cv;
        cv.u = make_uint4(pack2bf(a.x * qs, a.y * qs), pack2bf(a.z * qs, a.w * qs),
                          pack2bf(b.x * qs, b.y * qs), pack2bf(b.z * qs, b.w * qs));
        qf[s] = cv.v;
    }

    f32x16 O0 = {}, O1 = {};          // O[q-rows spread over regs][d = l31 + 32*db]
    float mrow = -1e30f;              // running max for q = l31 (log2 domain)
    float ol = 0.f;                   // running P-row sum for q = l31

    for (int it = 0; it < 16; it++) {
        // ---- stage K/V tile (sync, reg->LDS with swizzle)
        uint4 k0 = *(const uint4*)kp;
        uint4 k1 = *(const uint4*)(kp + 16 * 64);
        uint4 k2 = *(const uint4*)(kp + 32 * 64);
        uint4 k3 = *(const uint4*)(kp + 48 * 64);
        uint4 v0 = *(const uint4*)vp;
        uint4 v1 = *(const uint4*)(vp + (size_t)16 * 4096);
        uint4 v2 = *(const uint4*)(vp + (size_t)32 * 4096);
        uint4 v3 = *(const uint4*)(vp + (size_t)48 * 4096);
        kp += 4096; vp += 64;
        __syncthreads();
        *(uint4*)&Kt[sr][swz]      = k0;
        *(uint4*)&Kt[sr + 16][swz] = k1;
        *(uint4*)&Kt[sr + 32][swz] = k2;
        *(uint4*)&Kt[sr + 48][swz] = k3;
        *(uint4*)&Vt[sr][swz]      = v0;
        *(uint4*)&Vt[sr + 16][swz] = v1;
        *(uint4*)&Vt[sr + 32][swz] = v2;
        *(uint4*)&Vt[sr + 48][swz] = v3;
        __syncthreads();

        // ---- QK^T swapped: S[k][q] = mfma(A=K, B=Q); lane: q = l31,
        //      k-rows = (reg&3) + 8*(reg>>2) + 4*hi (+32 for S1)
        f32x16 S0 = {}, S1 = {};
        const int kcol = ((hi) ^ (l31 & 7));   // base window, s adds 2*s before XOR
        (void)kcol;
        __builtin_amdgcn_s_setprio(1);
        #pragma unroll
        for (int s = 0; s < 4; s++) {
            const int cc = ((2 * s + hi) ^ (l31 & 7)) << 3;
            bf16x8 kf0 = *(const bf16x8*)&Kt[l31][cc];
            bf16x8 kf1 = *(const bf16x8*)&Kt[l31 + 32][cc];
            S0 = __builtin_amdgcn_mfma_f32_32x32x16_bf16(kf0, qf[s], S0, 0, 0, 0);
            S1 = __builtin_amdgcn_mfma_f32_32x32x16_bf16(kf1, qf[s], S1, 0, 0, 0);
        }
        __builtin_amdgcn_s_setprio(0);

        // ---- lane-local row max (own 32 values) + combine with partner half
        float r[32];
        #pragma unroll
        for (int i = 0; i < 16; i++) { r[i] = S0[i]; r[16 + i] = S1[i]; }
        #pragma unroll
        for (int st = 16; st > 0; st >>= 1)
            #pragma unroll
            for (int i = 0; i < st; i++) r[i] = fmaxf(r[i], r[i + st]);
        float mx = fmaxf(r[0], __shfl_xor(r[0], 32));

        // T13 defer-max: rescale only when max grows by > 8 (log2 domain)
        if (__any(mx > mrow + 8.f)) {
            float mnew = fmaxf(mrow, mx);
            float alpha = __builtin_amdgcn_exp2f(mrow - mnew);
            mrow = mnew;
            ol *= alpha;
            #pragma unroll
            for (int rg = 0; rg < 16; rg++) {
                float ar = __shfl(alpha, (rg & 3) + 8 * (rg >> 2) + 4 * hi);
                O0[rg] *= ar;
                O1[rg] *= ar;
            }
        }

        // ---- P = exp2(S - mrow), in place
        #pragma unroll
        for (int i = 0; i < 16; i++) S0[i] = __builtin_amdgcn_exp2f(S0[i] - mrow);
        #pragma unroll
        for (int i = 0; i < 16; i++) S1[i] = __builtin_amdgcn_exp2f(S1[i] - mrow);

        // ---- l-sum: lane-local add tree + partner half
        float a2[32];
        #pragma unroll
        for (int i = 0; i < 16; i++) { a2[i] = S0[i]; a2[16 + i] = S1[i]; }
        #pragma unroll
        for (int st = 16; st > 0; st >>= 1)
            #pragma unroll
            for (int i = 0; i < st; i++) a2[i] += a2[i + st];
        ol += a2[0] + __shfl_xor(a2[0], 32);

        // ---- pack P to bf16, exchange halves, build PV A-fragments
        unsigned c[16], d[16];
        #pragma unroll
        for (int i = 0; i < 8; i++) c[i] = pack2bf(S0[2 * i], S0[2 * i + 1]);
        #pragma unroll
        for (int i = 0; i < 8; i++) c[8 + i] = pack2bf(S1[2 * i], S1[2 * i + 1]);
        #pragma unroll
        for (int i = 0; i < 16; i++) d[i] = __shfl_xor(c[i], 32);

        bf16x8 pa[4];
        #pragma unroll
        for (int b = 0; b < 2; b++) {
            union { uint4 u; bf16x8 v; } t0, t1;
            t0.u = make_uint4(hi ? d[8 * b + 2] : c[8 * b + 0],
                              hi ? d[8 * b + 3] : c[8 * b + 1],
                              hi ? c[8 * b + 2] : d[8 * b + 0],
                              hi ? c[8 * b + 3] : d[8 * b + 1]);
            t1.u = make_uint4(hi ? d[8 * b + 6] : c[8 * b + 4],
                              hi ? d[8 * b + 7] : c[8 * b + 5],
                              hi ? c[8 * b + 6] : d[8 * b + 4],
                              hi ? c[8 * b + 7] : d[8 * b + 5]);
            pa[2 * b] = t0.v;
            pa[2 * b + 1] = t1.v;
        }

        // ---- PV: O[q][d] += P[q][k] * V[k][d]
        __builtin_amdgcn_s_setprio(1);
        #pragma unroll
        for (int ks = 0; ks < 4; ks++) {
            const int cc = ((2 * ks + hi) ^ (l31 & 7)) << 3;
            bf16x8 vf0 = *(const bf16x8*)&Vt[l31][cc];
            bf16x8 vf1 = *(const bf16x8*)&Vt[l31 + 32][cc];
            O0 = __builtin_amdgcn_mfma_f32_32x32x16_bf16(pa[ks], vf0, O0, 0, 0, 0);
            O1 = __builtin_amdgcn_mfma_f32_32x32x16_bf16(pa[ks], vf1, O1, 0, 0, 0);
        }
        __builtin_amdgcn_s_setprio(0);
    }

    // ---- epilogue: store unnormalized partials + m/l
    #pragma unroll
    for (int rg = 0; rg < 16; rg++) {
        int q = q0 + w * 32 + (rg & 3) + 8 * (rg >> 2) + 4 * hi;
        size_t base = (size_t)q * 1536 + 512 + split * 256 + h * 64;
        opart[base + l31] = f2bf(O0[rg]);
        opart[base + 32 + l31] = f2bf(O1[rg]);
    }
    if (hi == 0) {
        m_part[(split * 4 + h) * 4096 + q0 + w * 32 + l31] = mrow;
        l_part[(split * 4 + h) * 4096 + q0 + w * 32 + l31] = ol;
    }
}

// merge 4 splits (m in log2 domain)
__global__ __launch_bounds__(256)
void attn_merge_k(const ushort_t* __restrict__ opart, const float* __restrict__ m_part,
                  const float* __restrict__ l_part, float* __restrict__ att)
{
    int idx = blockIdx.x * 256 + threadIdx.x;
    int q = idx >> 8, c = idx & 255;
    int h = c >> 6, d = c & 63;
    float ms[4];
    float mmax = -1e30f;
    #pragma unroll
    for (int s = 0; s < 4; s++) {
        ms[s] = m_part[(s * 4 + h) * 4096 + q];
        mmax = fmaxf(mmax, ms[s]);
    }
    float onum = 0.f, lden = 0.f;
    #pragma unroll
    for (int s = 0; s < 4; s++) {
        float wgt = __builtin_amdgcn_exp2f(ms[s] - mmax);
        float ov = bf2f(opart[(size_t)q * 1536 + 512 + s * 256 + h * 64 + d]);
        onum += wgt * ov;
        lden += wgt * l_part[(s * 4 + h) * 4096 + q];
    }
    att[(size_t)q * 256 + c] = onum / lden;
}

// ---------------- symmetrized final MLP, MFMA bf16 ----------------
__global__ __launch_bounds__(256)
void sym_mlp_mfma_k(const ushort_t* __restrict__ Tb, const ushort_t* __restrict__ Wb,
                    const float* __restrict__ b2, float* __restrict__ out)
{
    __shared__ ushort_t As[128][72];
    __shared__ ushort_t Bs[128][72];
    const int t = threadIdx.x;
    const int w = t >> 6, lane = t & 63;
    const int m = lane & 15, quad = lane >> 4;
    const int wr = (w >> 1) * 64, wc = (w & 1) * 64;
    const int ri = blockIdx.y * 128, rj = blockIdx.x * 128;

    f32x4 acc[4][4] = {};
    for (int kk = 0; kk < 8; kk++) {
        const int k0 = kk * 64;
        const ushort_t* Asrc = (k0 < 256) ? Tb : Wb;
        const ushort_t* Bsrc = (k0 < 256) ? Wb : Tb;
        const int kcol = k0 & 255;
        __syncthreads();
        #pragma unroll
        for (int i = 0; i < 4; i++) {
            int s = t + i * 256;
            int row = s >> 3, ch = (s & 7) * 8;
            *(uint4*)&As[row][ch] = *(const uint4*)&Asrc[(size_t)(ri + row) * 256 + kcol + ch];
            *(uint4*)&Bs[row][ch] = *(const uint4*)&Bsrc[(size_t)(rj + row) * 256 + kcol + ch];
        }
        __syncthreads();
        #pragma unroll
        for (int kc = 0; kc < 2; kc++) {
            bf16x8 af[4], bfr[4];
            #pragma unroll
            for (int rb = 0; rb < 4; rb++)
                af[rb] = *(const bf16x8*)&As[wr + rb * 16 + m][kc * 32 + quad * 8];
            #pragma unroll
            for (int cb = 0; cb < 4; cb++)
                bfr[cb] = *(const bf16x8*)&Bs[wc + cb * 16 + m][kc * 32 + quad * 8];
            #pragma unroll
            for (int rb = 0; rb < 4; rb++)
                #pragma unroll
                for (int cb = 0; cb < 4; cb++)
                    acc[rb][cb] = __builtin_amdgcn_mfma_f32_16x16x32_bf16(af[rb], bfr[cb], acc[rb][cb], 0, 0, 0);
        }
    }
    #pragma unroll
    for (int rb = 0; rb < 4; rb++) {
        #pragma unroll
        for (int r = 0; r < 4; r++) {
            const int gr = ri + wr + rb * 16 + quad * 4 + r;
            const float br = b2[gr];
            #pragma unroll
            for (int cb = 0; cb < 4; cb++) {
                const int gc = rj + wc + cb * 16 + m;
                out[(size_t)gr * NN + gc] = 0.5f * (acc[rb][cb][r] + br + b2[gc]);
            }
        }
    }
}

// ---------------- launch ----------------
extern "C" void kernel_launch(void* const* d_in, const int* in_sizes, int n_in,
                              void* d_out, int out_size, void* d_ws, size_t ws_size,
                              hipStream_t stream) {
    (void)in_sizes; (void)n_in; (void)out_size; (void)ws_size;
    const float* x = (const float*)d_in[0];
    const int* ei = (const int*)d_in[1];
    const int* src = ei;
    const int* dst = ei + EE;

    float* ws = (float*)d_ws;
    const int NH = NN * HC;          // 1,048,576 floats
    float* h0  = ws;
    float* hb  = ws + 1 * NH;
    float* hc  = ws + 2 * NH;
    float* att = ws + 3 * NH;
    float* qkv = ws + 4 * NH;
    float* ffh = ws + 4 * NH;        // reuses qkv region (dead by then)
    float* deg = ws + 7 * NH;
    float* dinv = deg + NN;
    int* offs    = (int*)(dinv + NN);
    int* cursor  = offs + 4100;
    int* csr_src = cursor + 4096;
    float* m_part = (float*)(csr_src + EE);
    float* l_part = m_part + 65536;
    ushort_t* Kb  = (ushort_t*)hc;
    ushort_t* Vtb = Kb + NH;
    ushort_t* Tb  = (ushort_t*)hb;
    ushort_t* W2b = Tb + NH;

    deg_init_k<<<NN / 256, 256, 0, stream>>>(deg);
    deg_scatter_k<<<EE / 256, 256, 0, stream>>>(dst, deg);
    dinv_k<<<NN / 256, 256, 0, stream>>>(deg, dinv);
    scan_offsets_k<<<1, 1024, 0, stream>>>(deg, offs, cursor);
    csr_fill_k<<<EE / 256, 256, 0, stream>>>(src, dst, cursor, csr_src);

    // pre: h0 = relu(x @ pre_w^T + pre_b)
    gemm_bf_k<<<dim3(8, 64), 256, 0, stream>>>(
        x, (const float*)d_in[2], (const float*)d_in[3], nullptr,
        nullptr, nullptr, 0.f, h0, 128, 256, 1, 0,
        0, nullptr, nullptr, nullptr, 0);

    for (int L = 0; L < 2; L++) {
        int B = 4 + L * 10;
        const float* gw = (const float*)d_in[B + 0];
        const float* gb = (const float*)d_in[B + 1];
        const float* iw = (const float*)d_in[B + 2];
        const float* ib = (const float*)d_in[B + 3];
        const float* ow = (const float*)d_in[B + 4];
        const float* ob = (const float*)d_in[B + 5];
        const float* w1 = (const float*)d_in[B + 6];
        const float* b1 = (const float*)d_in[B + 7];
        const float* w2 = (const float*)d_in[B + 8];
        const float* b2 = (const float*)d_in[B + 9];

        // fused: cols 0-255 = h0@gw^T -> att(xw); cols 256-1023 = h0@iw^T+ib -> qkv
        gemm_bf_k<<<dim3(32, 64), 256, 0, stream>>>(
            h0, gw, nullptr, nullptr, nullptr, nullptr, 0.f, att, 256, 256, 0, 0,
            256, iw, ib, qkv, 768);
        gcn_gather_k<<<NN / 4, 256, 0, stream>>>(att, dinv, offs, csr_src, hb);
        kv_prep_k<<<dim3(64, 4), 256, 0, stream>>>(qkv, Kb, Vtb);
        attn_part_k<<<dim3(64, 16), 128, 0, stream>>>(
            qkv, Kb, Vtb, (ushort_t*)qkv, m_part, l_part);
        attn_merge_k<<<NN, 256, 0, stream>>>(
            (const ushort_t*)qkv, m_part, l_part, att);
        gemm_bf_k<<<dim3(8, 64), 256, 0, stream>>>(
            att, ow, ob, gb, hb, h0, 2.0f, hc, 256, 256, 0, 0,
            0, nullptr, nullptr, nullptr, 0);
        gemm_bf_k<<<dim3(16, 64), 256, 0, stream>>>(
            hc, w1, b1, nullptr, nullptr, nullptr, 0.f, ffh, 256, 512, 1, 0,
            0, nullptr, nullptr, nullptr, 0);
        gemm_bf_k<<<dim3(8, 64), 256, 0, stream>>>(
            ffh, w2, b2, nullptr, hc, nullptr, 0.f, h0, 512, 256, 1, 0,
            0, nullptr, nullptr, nullptr, 0);
    }

    // Tb(bf16) = relu(h0 @ mlp_w1^T + mlp_b1)
    gemm_bf_k<<<dim3(8, 64), 256, 0, stream>>>(
        h0, (const float*)d_in[24], (const float*)d_in[25], nullptr,
        nullptr, nullptr, 0.f, (float*)Tb, 256, 256, 1, 1,
        0, nullptr, nullptr, nullptr, 0);
    // W2b = bf16(mlp_w2)
    cvt_bf16_k<<<NH / 1024, 256, 0, stream>>>((const float*)d_in[26], W2b);
    // out = 0.5*(delta + delta^T) via K=512 concat GEMM
    sym_mlp_mfma_k<<<dim3(32, 32), 256, 0, stream>>>(
        Tb, W2b, (const float*)d_in[27], (float*)d_out);
}

// Round 4
// 412.463 us; speedup vs baseline: 1.0897x; 1.0183x over previous
//
#include <hip/hip_runtime.h>

#define NN 4096
#define EE 65536
#define HC 256   // hidden channels

typedef unsigned short ushort_t;
typedef __attribute__((ext_vector_type(8))) short bf16x8;
typedef __attribute__((ext_vector_type(4))) float f32x4;
typedef __attribute__((ext_vector_type(16))) float f32x16;

__device__ __forceinline__ ushort_t f2bf(float f) {
    unsigned int u = __float_as_uint(f);
    unsigned int r = (u + 0x7fffu + ((u >> 16) & 1u)) >> 16;
    return (ushort_t)r;
}
__device__ __forceinline__ float bf2f(ushort_t u) {
    return __uint_as_float(((unsigned int)u) << 16);
}
// pack two floats to bf16 pair (round-half-up), a in low 16 (lower address)
__device__ __forceinline__ unsigned int pack2bf(float a, float b) {
    unsigned int ua = __float_as_uint(a) + 0x8000u;
    unsigned int ub = __float_as_uint(b) + 0x8000u;
    return __builtin_amdgcn_perm(ub, ua, 0x07060302u);
}

// ---------------- degree / CSR build ----------------
__global__ void deg_init_k(float* __restrict__ deg) {
    int i = blockIdx.x * 256 + threadIdx.x;
    deg[i] = 1.0f;  // self loop
}
__global__ void deg_scatter_k(const int* __restrict__ dst, float* __restrict__ deg) {
    int e = blockIdx.x * 256 + threadIdx.x;
    atomicAdd(&deg[dst[e]], 1.0f);
}
__global__ void dinv_k(const float* __restrict__ deg, float* __restrict__ dinv) {
    int i = blockIdx.x * 256 + threadIdx.x;
    dinv[i] = rsqrtf(deg[i]);
}
__global__ __launch_bounds__(1024)
void scan_offsets_k(const float* __restrict__ deg, int* __restrict__ offs,
                    int* __restrict__ cursor) {
    __shared__ int part[1024];
    const int t = threadIdx.x;
    int c0 = (int)deg[t * 4 + 0] - 1;
    int c1 = (int)deg[t * 4 + 1] - 1;
    int c2 = (int)deg[t * 4 + 2] - 1;
    int c3 = (int)deg[t * 4 + 3] - 1;
    part[t] = c0 + c1 + c2 + c3;
    __syncthreads();
    for (int off = 1; off < 1024; off <<= 1) {
        int v = (t >= off) ? part[t - off] : 0;
        __syncthreads();
        part[t] += v;
        __syncthreads();
    }
    int base = (t == 0) ? 0 : part[t - 1];
    offs[t * 4 + 0] = base;
    offs[t * 4 + 1] = base + c0;
    offs[t * 4 + 2] = base + c0 + c1;
    offs[t * 4 + 3] = base + c0 + c1 + c2;
    cursor[t * 4 + 0] = base;
    cursor[t * 4 + 1] = base + c0;
    cursor[t * 4 + 2] = base + c0 + c1;
    cursor[t * 4 + 3] = base + c0 + c1 + c2;
    if (t == 1023) offs[4096] = part[1023];
}
__global__ void csr_fill_k(const int* __restrict__ src, const int* __restrict__ dst,
                           int* __restrict__ cursor, int* __restrict__ csr_src) {
    int e = blockIdx.x * 256 + threadIdx.x;
    int pos = atomicAdd(&cursor[dst[e]], 1);
    csr_src[pos] = src[e];
}

// ---------------- GCN gather ----------------
__global__ __launch_bounds__(256)
void gcn_gather_k(const float* __restrict__ xw, const float* __restrict__ dinv,
                  const int* __restrict__ offs, const int* __restrict__ csr_src,
                  float* __restrict__ agg) {
    const int node = blockIdx.x * 4 + (threadIdx.x >> 6);
    const int c = (threadIdx.x & 63) * 4;
    const float dd = dinv[node];
    float4 a = *(const float4*)&xw[(size_t)node * HC + c];
    const float self = dd * dd;
    float4 acc = make_float4(a.x * self, a.y * self, a.z * self, a.w * self);
    const int beg = offs[node], end = offs[node + 1];
    for (int e = beg; e < end; e++) {
        int s = csr_src[e];
        float coef = dinv[s] * dd;
        const float4 v = *(const float4*)&xw[(size_t)s * HC + c];
        acc.x += v.x * coef;
        acc.y += v.y * coef;
        acc.z += v.z * coef;
        acc.w += v.w * coef;
    }
    *(float4*)&agg[(size_t)node * HC + c] = acc;
}

// ---------------- fp32 -> bf16 convert ----------------
__global__ void cvt_bf16_k(const float* __restrict__ in, ushort_t* __restrict__ out) {
    int i = (blockIdx.x * 256 + threadIdx.x) * 4;
    float4 v = *(const float4*)&in[i];
    unsigned int d0 = pack2bf(v.x, v.y), d1 = pack2bf(v.z, v.w);
    *(uint2*)&out[i] = make_uint2(d0, d1);
}

// ---------------- bf16-MFMA GEMM, 64row x 32col tile (2 blocks/CU+), dual region ----
__global__ __launch_bounds__(256)
void gemm_bf_k(const float* __restrict__ X, const float* __restrict__ W,
               const float* __restrict__ bias1, const float* __restrict__ bias2,
               const float* __restrict__ res1, const float* __restrict__ res2, float res2scale,
               float* __restrict__ out, int K, int M, int dorelu, int obf,
               int colsplit, const float* __restrict__ W2,
               const float* __restrict__ bias_r2, float* __restrict__ out2, int M2)
{
    __shared__ ushort_t As[64][72];
    __shared__ ushort_t Bs[32][72];
    const int t = threadIdx.x;
    const int w = t >> 6, lane = t & 63;
    const int m = lane & 15, quad = lane >> 4;
    const int row0 = blockIdx.y << 6, col0 = blockIdx.x << 5;   // 32-col tiles
    const int sr = t >> 2;
    const int sc = (t & 3) << 4;
    const int wr2 = t >> 3;           // W staging row 0..31
    const int wc2 = (t & 7) << 3;     // W staging k-chunk 0,8,...,56

    const float* Wu = W;
    const float* b1u = bias1;
    const float* b2u = bias2;
    float* outu = out;
    int Mu = M, colu = col0;
    if (colsplit > 0 && col0 >= colsplit) {
        Wu = W2; b1u = bias_r2; b2u = nullptr;
        outu = out2; Mu = M2; colu = col0 - colsplit;
    }

    f32x4 acc[2] = {};
    for (int k0 = 0; k0 < K; k0 += 64) {
        const float* xp = &X[(size_t)(row0 + sr) * K + k0 + sc];
        const float* wp = &Wu[(size_t)(colu + wr2) * K + k0 + wc2];
        float4 xa = *(const float4*)xp,       xb = *(const float4*)(xp + 4);
        float4 xc = *(const float4*)(xp + 8), xd = *(const float4*)(xp + 12);
        float4 wa = *(const float4*)wp,       wb = *(const float4*)(wp + 4);
        __syncthreads();
        {
            unsigned int tx[8];
            tx[0] = pack2bf(xa.x, xa.y); tx[1] = pack2bf(xa.z, xa.w);
            tx[2] = pack2bf(xb.x, xb.y); tx[3] = pack2bf(xb.z, xb.w);
            tx[4] = pack2bf(xc.x, xc.y); tx[5] = pack2bf(xc.z, xc.w);
            tx[6] = pack2bf(xd.x, xd.y); tx[7] = pack2bf(xd.z, xd.w);
            *(uint4*)&As[sr][sc]     = *(const uint4*)&tx[0];
            *(uint4*)&As[sr][sc + 8] = *(const uint4*)&tx[4];
            unsigned int tw[4];
            tw[0] = pack2bf(wa.x, wa.y); tw[1] = pack2bf(wa.z, wa.w);
            tw[2] = pack2bf(wb.x, wb.y); tw[3] = pack2bf(wb.z, wb.w);
            *(uint4*)&Bs[wr2][wc2] = *(const uint4*)&tw[0];
        }
        __syncthreads();
        #pragma unroll
        for (int kc = 0; kc < 2; kc++) {
            bf16x8 af = *(const bf16x8*)&As[(w << 4) + m][kc * 32 + quad * 8];
            #pragma unroll
            for (int cb = 0; cb < 2; cb++) {
                bf16x8 bf = *(const bf16x8*)&Bs[cb * 16 + m][kc * 32 + quad * 8];
                acc[cb] = __builtin_amdgcn_mfma_f32_16x16x32_bf16(af, bf, acc[cb], 0, 0, 0);
            }
        }
    }
    #pragma unroll
    for (int cb = 0; cb < 2; cb++) {
        #pragma unroll
        for (int r = 0; r < 4; r++) {
            const int row = row0 + (w << 4) + quad * 4 + r;
            const int col = colu + cb * 16 + m;
            float v = acc[cb][r];
            if (b1u) v += b1u[col];
            if (b2u) v += b2u[col];
            if (res1) v += res1[(size_t)row * Mu + col];
            if (res2) v += res2scale * res2[(size_t)row * Mu + col];
            if (dorelu) v = fmaxf(v, 0.f);
            if (obf) ((ushort_t*)outu)[(size_t)row * Mu + col] = f2bf(v);
            else outu[(size_t)row * Mu + col] = v;
        }
    }
}

// ---------------- K/V bf16 prep: Kb[h][n][d], Vtb[h][d][n] ----------------
__global__ __launch_bounds__(256)
void kv_prep_k(const float* __restrict__ qkv, ushort_t* __restrict__ Kb,
               ushort_t* __restrict__ Vtb)
{
    __shared__ ushort_t Vs[64][72];
    const int h = blockIdx.y;
    const int n0 = blockIdx.x << 6;
    const int t = threadIdx.x;
    for (int u = t; u < 1024; u += 256) {
        int r = u >> 4, c = u & 15;
        const float* kp = &qkv[(size_t)(n0 + r) * 768 + 256 + h * 64 + c * 4];
        float4 kv = *(const float4*)kp;
        float4 vv = *(const float4*)(kp + 256);
        *(uint2*)&Kb[((size_t)(h * 4096 + n0 + r)) * 64 + c * 4] =
            make_uint2(pack2bf(kv.x, kv.y), pack2bf(kv.z, kv.w));
        *(uint2*)&Vs[r][c * 4] =
            make_uint2(pack2bf(vv.x, vv.y), pack2bf(vv.z, vv.w));
    }
    __syncthreads();
    int d = t >> 2, kc = t & 3;
    __attribute__((aligned(16))) ushort_t vals[16];
    #pragma unroll
    for (int k = 0; k < 16; k++) vals[k] = Vs[kc * 16 + k][d];
    ushort_t* op = &Vtb[((size_t)(h * 64 + d)) * 4096 + n0 + kc * 16];
    *(uint4*)op = *(const uint4*)&vals[0];
    *(uint4*)(op + 8) = *(const uint4*)&vals[8];
}

// ---------------- split-K MFMA flash attention partials (exp2 domain) ----------------
// v5: v4's swapped-QK^T 32x32x16 structure + (a) 128 q per block (4 warps, halves
//     L2 re-read traffic), (b) K/V double-buffered in LDS with ONE raw lgkm-only
//     barrier per iteration (no vmcnt drain in the loop; ds_write's operand regs
//     were loaded a full iteration earlier, so the compiler's counted vmcnt wait
//     is already satisfied). Keeps T13 defer-max and T5 setprio.
__global__ __launch_bounds__(256, 2)
void attn_part_k(const float* qkv, const ushort_t* __restrict__ Kb,
                 const ushort_t* __restrict__ Vtb, ushort_t* opart,
                 float* __restrict__ m_part, float* __restrict__ l_part)
{
    __shared__ ushort_t Kt[2][64][64];   // [buf][k][d], col16 ^= (row&7)
    __shared__ ushort_t Vt[2][64][64];   // [buf][d][k], col16 ^= (row&7)
    const int h = blockIdx.y & 3;
    const int split = blockIdx.y >> 2;
    const int q0 = blockIdx.x << 7;      // 128 q per block
    const int t = threadIdx.x;
    const int w = t >> 6;
    const int lane = t & 63;
    const int l31 = lane & 31;
    const int hi = lane >> 5;

    // staging geometry: thread covers rows sr, sr+32, 16B chunk sc
    const int sr = t >> 3;               // 0..31
    const int sc = t & 7;
    const int swz = ((sc ^ (sr & 7)) << 3);   // (sr+32)&7 == sr&7
    const ushort_t* kp = &Kb[((size_t)(h * 4096 + split * 1024 + sr)) * 64 + sc * 8];
    const ushort_t* vp = &Vtb[((size_t)(h * 64 + sr)) * 4096 + split * 1024 + sc * 8];

    // Q fragments (B-operand): lane holds Q[d = s*16 + hi*8 + j][q = l31]
    const float qs = 0.125f * 1.44269504f;
    const int qrow = q0 + w * 32 + l31;
    bf16x8 qf[4];
    #pragma unroll
    for (int s = 0; s < 4; s++) {
        const float* qp = &qkv[(size_t)qrow * 768 + h * 64 + s * 16 + hi * 8];
        float4 a = *(const float4*)qp;
        float4 b = *(const float4*)(qp + 4);
        union { uint4 u; bf16x8 v; } cv;
        cv.u = make_uint4(pack2bf(a.x * qs, a.y * qs), pack2bf(a.z * qs, a.w * qs),
                          pack2bf(b.x * qs, b.y * qs), pack2bf(b.z * qs, b.w * qs));
        qf[s] = cv.v;
    }

    f32x16 O0 = {}, O1 = {};             // O[q-rows over regs][d = l31 + 32*db]
    float mrow = -1e30f;                 // running max for q = l31 (log2 domain)
    float ol = 0.f;                      // running P-row sum for q = l31

    // ---- prologue: tile0 -> LDS[0]; tile1 loads in flight in regs
    uint4 ka0 = *(const uint4*)kp;
    uint4 ka1 = *(const uint4*)(kp + 32 * 64);
    uint4 va0 = *(const uint4*)vp;
    uint4 va1 = *(const uint4*)(vp + (size_t)32 * 4096);
    kp += 4096; vp += 64;
    *(uint4*)&Kt[0][sr][swz]      = ka0;
    *(uint4*)&Kt[0][sr + 32][swz] = ka1;
    *(uint4*)&Vt[0][sr][swz]      = va0;
    *(uint4*)&Vt[0][sr + 32][swz] = va1;
    ka0 = *(const uint4*)kp;
    ka1 = *(const uint4*)(kp + 32 * 64);
    va0 = *(const uint4*)vp;
    va1 = *(const uint4*)(vp + (size_t)32 * 4096);
    kp += 4096; vp += 64;
    asm volatile("s_waitcnt lgkmcnt(0)" ::: "memory");
    __builtin_amdgcn_s_barrier();

    for (int it = 0; it < 16; it++) {
        const int cur = it & 1;

        // ---- QK^T swapped: S[k][q] = mfma(A=K, B=Q); lane: q = l31,
        //      k-rows = (reg&3) + 8*(reg>>2) + 4*hi (+32 for S1)
        f32x16 S0 = {}, S1 = {};
        __builtin_amdgcn_s_setprio(1);
        #pragma unroll
        for (int s = 0; s < 4; s++) {
            const int cc = ((2 * s + hi) ^ (l31 & 7)) << 3;
            bf16x8 kf0 = *(const bf16x8*)&Kt[cur][l31][cc];
            bf16x8 kf1 = *(const bf16x8*)&Kt[cur][l31 + 32][cc];
            S0 = __builtin_amdgcn_mfma_f32_32x32x16_bf16(kf0, qf[s], S0, 0, 0, 0);
            S1 = __builtin_amdgcn_mfma_f32_32x32x16_bf16(kf1, qf[s], S1, 0, 0, 0);
        }
        __builtin_amdgcn_s_setprio(0);

        // ---- lane-local row max (own 32 values) + combine with partner half
        float r[32];
        #pragma unroll
        for (int i = 0; i < 16; i++) { r[i] = S0[i]; r[16 + i] = S1[i]; }
        #pragma unroll
        for (int st = 16; st > 0; st >>= 1)
            #pragma unroll
            for (int i = 0; i < st; i++) r[i] = fmaxf(r[i], r[i + st]);
        float mx = fmaxf(r[0], __shfl_xor(r[0], 32));

        // T13 defer-max: rescale only when max grows by > 8 (log2 domain)
        if (__any(mx > mrow + 8.f)) {
            float mnew = fmaxf(mrow, mx);
            float alpha = __builtin_amdgcn_exp2f(mrow - mnew);
            mrow = mnew;
            ol *= alpha;
            #pragma unroll
            for (int rg = 0; rg < 16; rg++) {
                float ar = __shfl(alpha, (rg & 3) + 8 * (rg >> 2) + 4 * hi);
                O0[rg] *= ar;
                O1[rg] *= ar;
            }
        }

        // ---- P = exp2(S - mrow), in place
        #pragma unroll
        for (int i = 0; i < 16; i++) S0[i] = __builtin_amdgcn_exp2f(S0[i] - mrow);
        #pragma unroll
        for (int i = 0; i < 16; i++) S1[i] = __builtin_amdgcn_exp2f(S1[i] - mrow);

        // ---- l-sum: lane-local add tree + partner half
        float a2[32];
        #pragma unroll
        for (int i = 0; i < 16; i++) { a2[i] = S0[i]; a2[16 + i] = S1[i]; }
        #pragma unroll
        for (int st = 16; st > 0; st >>= 1)
            #pragma unroll
            for (int i = 0; i < st; i++) a2[i] += a2[i + st];
        ol += a2[0] + __shfl_xor(a2[0], 32);

        // ---- stage tile it+1 into the other buffer; issue loads for tile it+2
        //      (regs ka0..va1 were loaded a full iteration ago -> counted vmcnt
        //       wait already satisfied; new loads ride under PV + next QK)
        if (it < 15) {
            *(uint4*)&Kt[cur ^ 1][sr][swz]      = ka0;
            *(uint4*)&Kt[cur ^ 1][sr + 32][swz] = ka1;
            *(uint4*)&Vt[cur ^ 1][sr][swz]      = va0;
            *(uint4*)&Vt[cur ^ 1][sr + 32][swz] = va1;
            if (it < 14) {
                ka0 = *(const uint4*)kp;
                ka1 = *(const uint4*)(kp + 32 * 64);
                va0 = *(const uint4*)vp;
                va1 = *(const uint4*)(vp + (size_t)32 * 4096);
                kp += 4096; vp += 64;
            }
        }

        // ---- pack P to bf16, exchange halves, build PV A-fragments
        unsigned c[16], d[16];
        #pragma unroll
        for (int i = 0; i < 8; i++) c[i] = pack2bf(S0[2 * i], S0[2 * i + 1]);
        #pragma unroll
        for (int i = 0; i < 8; i++) c[8 + i] = pack2bf(S1[2 * i], S1[2 * i + 1]);
        #pragma unroll
        for (int i = 0; i < 16; i++) d[i] = __shfl_xor(c[i], 32);

        bf16x8 pa[4];
        #pragma unroll
        for (int b = 0; b < 2; b++) {
            union { uint4 u; bf16x8 v; } t0, t1;
            t0.u = make_uint4(hi ? d[8 * b + 2] : c[8 * b + 0],
                              hi ? d[8 * b + 3] : c[8 * b + 1],
                              hi ? c[8 * b + 2] : d[8 * b + 0],
                              hi ? c[8 * b + 3] : d[8 * b + 1]);
            t1.u = make_uint4(hi ? d[8 * b + 6] : c[8 * b + 4],
                              hi ? d[8 * b + 7] : c[8 * b + 5],
                              hi ? c[8 * b + 6] : d[8 * b + 4],
                              hi ? c[8 * b + 7] : d[8 * b + 5]);
            pa[2 * b] = t0.v;
            pa[2 * b + 1] = t1.v;
        }

        // ---- PV: O[q][d] += P[q][k] * V[k][d]
        __builtin_amdgcn_s_setprio(1);
        #pragma unroll
        for (int ks = 0; ks < 4; ks++) {
            const int cc = ((2 * ks + hi) ^ (l31 & 7)) << 3;
            bf16x8 vf0 = *(const bf16x8*)&Vt[cur][l31][cc];
            bf16x8 vf1 = *(const bf16x8*)&Vt[cur][l31 + 32][cc];
            O0 = __builtin_amdgcn_mfma_f32_32x32x16_bf16(pa[ks], vf0, O0, 0, 0, 0);
            O1 = __builtin_amdgcn_mfma_f32_32x32x16_bf16(pa[ks], vf1, O1, 0, 0, 0);
        }
        __builtin_amdgcn_s_setprio(0);

        // ---- single barrier per iteration (lgkm only; loads stay in flight)
        asm volatile("s_waitcnt lgkmcnt(0)" ::: "memory");
        __builtin_amdgcn_s_barrier();
    }

    // ---- epilogue: store unnormalized partials + m/l
    #pragma unroll
    for (int rg = 0; rg < 16; rg++) {
        int q = q0 + w * 32 + (rg & 3) + 8 * (rg >> 2) + 4 * hi;
        size_t base = (size_t)q * 1536 + 512 + split * 256 + h * 64;
        opart[base + l31] = f2bf(O0[rg]);
        opart[base + 32 + l31] = f2bf(O1[rg]);
    }
    if (hi == 0) {
        m_part[(split * 4 + h) * 4096 + q0 + w * 32 + l31] = mrow;
        l_part[(split * 4 + h) * 4096 + q0 + w * 32 + l31] = ol;
    }
}

// merge 4 splits (m in log2 domain)
__global__ __launch_bounds__(256)
void attn_merge_k(const ushort_t* __restrict__ opart, const float* __restrict__ m_part,
                  const float* __restrict__ l_part, float* __restrict__ att)
{
    int idx = blockIdx.x * 256 + threadIdx.x;
    int q = idx >> 8, c = idx & 255;
    int h = c >> 6, d = c & 63;
    float ms[4];
    float mmax = -1e30f;
    #pragma unroll
    for (int s = 0; s < 4; s++) {
        ms[s] = m_part[(s * 4 + h) * 4096 + q];
        mmax = fmaxf(mmax, ms[s]);
    }
    float onum = 0.f, lden = 0.f;
    #pragma unroll
    for (int s = 0; s < 4; s++) {
        float wgt = __builtin_amdgcn_exp2f(ms[s] - mmax);
        float ov = bf2f(opart[(size_t)q * 1536 + 512 + s * 256 + h * 64 + d]);
        onum += wgt * ov;
        lden += wgt * l_part[(s * 4 + h) * 4096 + q];
    }
    att[(size_t)q * 256 + c] = onum / lden;
}

// ---------------- symmetrized final MLP, MFMA bf16 ----------------
__global__ __launch_bounds__(256)
void sym_mlp_mfma_k(const ushort_t* __restrict__ Tb, const ushort_t* __restrict__ Wb,
                    const float* __restrict__ b2, float* __restrict__ out)
{
    __shared__ ushort_t As[128][72];
    __shared__ ushort_t Bs[128][72];
    const int t = threadIdx.x;
    const int w = t >> 6, lane = t & 63;
    const int m = lane & 15, quad = lane >> 4;
    const int wr = (w >> 1) * 64, wc = (w & 1) * 64;
    const int ri = blockIdx.y * 128, rj = blockIdx.x * 128;

    f32x4 acc[4][4] = {};
    for (int kk = 0; kk < 8; kk++) {
        const int k0 = kk * 64;
        const ushort_t* Asrc = (k0 < 256) ? Tb : Wb;
        const ushort_t* Bsrc = (k0 < 256) ? Wb : Tb;
        const int kcol = k0 & 255;
        __syncthreads();
        #pragma unroll
        for (int i = 0; i < 4; i++) {
            int s = t + i * 256;
            int row = s >> 3, ch = (s & 7) * 8;
            *(uint4*)&As[row][ch] = *(const uint4*)&Asrc[(size_t)(ri + row) * 256 + kcol + ch];
            *(uint4*)&Bs[row][ch] = *(const uint4*)&Bsrc[(size_t)(rj + row) * 256 + kcol + ch];
        }
        __syncthreads();
        #pragma unroll
        for (int kc = 0; kc < 2; kc++) {
            bf16x8 af[4], bfr[4];
            #pragma unroll
            for (int rb = 0; rb < 4; rb++)
                af[rb] = *(const bf16x8*)&As[wr + rb * 16 + m][kc * 32 + quad * 8];
            #pragma unroll
            for (int cb = 0; cb < 4; cb++)
                bfr[cb] = *(const bf16x8*)&Bs[wc + cb * 16 + m][kc * 32 + quad * 8];
            #pragma unroll
            for (int rb = 0; rb < 4; rb++)
                #pragma unroll
                for (int cb = 0; cb < 4; cb++)
                    acc[rb][cb] = __builtin_amdgcn_mfma_f32_16x16x32_bf16(af[rb], bfr[cb], acc[rb][cb], 0, 0, 0);
        }
    }
    #pragma unroll
    for (int rb = 0; rb < 4; rb++) {
        #pragma unroll
        for (int r = 0; r < 4; r++) {
            const int gr = ri + wr + rb * 16 + quad * 4 + r;
            const float br = b2[gr];
            #pragma unroll
            for (int cb = 0; cb < 4; cb++) {
                const int gc = rj + wc + cb * 16 + m;
                out[(size_t)gr * NN + gc] = 0.5f * (acc[rb][cb][r] + br + b2[gc]);
            }
        }
    }
}

// ---------------- launch ----------------
extern "C" void kernel_launch(void* const* d_in, const int* in_sizes, int n_in,
                              void* d_out, int out_size, void* d_ws, size_t ws_size,
                              hipStream_t stream) {
    (void)in_sizes; (void)n_in; (void)out_size; (void)ws_size;
    const float* x = (const float*)d_in[0];
    const int* ei = (const int*)d_in[1];
    const int* src = ei;
    const int* dst = ei + EE;

    float* ws = (float*)d_ws;
    const int NH = NN * HC;          // 1,048,576 floats
    float* h0  = ws;
    float* hb  = ws + 1 * NH;
    float* hc  = ws + 2 * NH;
    float* att = ws + 3 * NH;
    float* qkv = ws + 4 * NH;
    float* ffh = ws + 4 * NH;        // reuses qkv region (dead by then)
    float* deg = ws + 7 * NH;
    float* dinv = deg + NN;
    int* offs    = (int*)(dinv + NN);
    int* cursor  = offs + 4100;
    int* csr_src = cursor + 4096;
    float* m_part = (float*)(csr_src + EE);
    float* l_part = m_part + 65536;
    ushort_t* Kb  = (ushort_t*)hc;
    ushort_t* Vtb = Kb + NH;
    ushort_t* Tb  = (ushort_t*)hb;
    ushort_t* W2b = Tb + NH;

    deg_init_k<<<NN / 256, 256, 0, stream>>>(deg);
    deg_scatter_k<<<EE / 256, 256, 0, stream>>>(dst, deg);
    dinv_k<<<NN / 256, 256, 0, stream>>>(deg, dinv);
    scan_offsets_k<<<1, 1024, 0, stream>>>(deg, offs, cursor);
    csr_fill_k<<<EE / 256, 256, 0, stream>>>(src, dst, cursor, csr_src);

    // pre: h0 = relu(x @ pre_w^T + pre_b)
    gemm_bf_k<<<dim3(8, 64), 256, 0, stream>>>(
        x, (const float*)d_in[2], (const float*)d_in[3], nullptr,
        nullptr, nullptr, 0.f, h0, 128, 256, 1, 0,
        0, nullptr, nullptr, nullptr, 0);

    for (int L = 0; L < 2; L++) {
        int B = 4 + L * 10;
        const float* gw = (const float*)d_in[B + 0];
        const float* gb = (const float*)d_in[B + 1];
        const float* iw = (const float*)d_in[B + 2];
        const float* ib = (const float*)d_in[B + 3];
        const float* ow = (const float*)d_in[B + 4];
        const float* ob = (const float*)d_in[B + 5];
        const float* w1 = (const float*)d_in[B + 6];
        const float* b1 = (const float*)d_in[B + 7];
        const float* w2 = (const float*)d_in[B + 8];
        const float* b2 = (const float*)d_in[B + 9];

        // fused: cols 0-255 = h0@gw^T -> att(xw); cols 256-1023 = h0@iw^T+ib -> qkv
        gemm_bf_k<<<dim3(32, 64), 256, 0, stream>>>(
            h0, gw, nullptr, nullptr, nullptr, nullptr, 0.f, att, 256, 256, 0, 0,
            256, iw, ib, qkv, 768);
        gcn_gather_k<<<NN / 4, 256, 0, stream>>>(att, dinv, offs, csr_src, hb);
        kv_prep_k<<<dim3(64, 4), 256, 0, stream>>>(qkv, Kb, Vtb);
        attn_part_k<<<dim3(32, 16), 256, 0, stream>>>(
            qkv, Kb, Vtb, (ushort_t*)qkv, m_part, l_part);
        attn_merge_k<<<NN, 256, 0, stream>>>(
            (const ushort_t*)qkv, m_part, l_part, att);
        gemm_bf_k<<<dim3(8, 64), 256, 0, stream>>>(
            att, ow, ob, gb, hb, h0, 2.0f, hc, 256, 256, 0, 0,
            0, nullptr, nullptr, nullptr, 0);
        gemm_bf_k<<<dim3(16, 64), 256, 0, stream>>>(
            hc, w1, b1, nullptr, nullptr, nullptr, 0.f, ffh, 256, 512, 1, 0,
            0, nullptr, nullptr, nullptr, 0);
        gemm_bf_k<<<dim3(8, 64), 256, 0, stream>>>(
            ffh, w2, b2, nullptr, hc, nullptr, 0.f, h0, 512, 256, 1, 0,
            0, nullptr, nullptr, nullptr, 0);
    }

    // Tb(bf16) = relu(h0 @ mlp_w1^T + mlp_b1)
    gemm_bf_k<<<dim3(8, 64), 256, 0, stream>>>(
        h0, (const float*)d_in[24], (const float*)d_in[25], nullptr,
        nullptr, nullptr, 0.f, (float*)Tb, 256, 256, 1, 1,
        0, nullptr, nullptr, nullptr, 0);
    // W2b = bf16(mlp_w2)
    cvt_bf16_k<<<NH / 1024, 256, 0, stream>>>((const float*)d_in[26], W2b);
    // out = 0.5*(delta + delta^T) via K=512 concat GEMM
    sym_mlp_mfma_k<<<dim3(32, 32), 256, 0, stream>>>(
        Tb, W2b, (const float*)d_in[27], (float*)d_out);
}